// Round 3
// baseline (193.601 us; speedup 1.0000x reference)
//
#include <hip/hip_runtime.h>

// BackwardRPM: 16384 independent solves, 200 steps of
//   u <- clip(u - LR * (R^T (R (tanh(u W1 + b1) W2 + b2 - spec)))[:6])
// Algebra: fold R out. Qs = -LR * W2 R^T R[:, :6]  (64x6),
//          Ss = -LR * R[:, :6]^T R (6x40), es = Ss (b2 - spec) per sample.
// Step: t = u W1 + b1; h = tanh(t); u = clip(u + h Qs + es).
//
// R3: 8 threads/sample. Constants PINNED in VGPRs via asm barrier (R1/R2 the
// compiler rematerialized LDS/global loads inside the 200-step loop: VGPR=64,
// 507k LDS bank conflicts). Reduction all-DPP: xor1 (quad_perm), xor2
// (quad_perm), xor7 (row_half_mirror 0x141) -- masks {1,2,7} generate the
// 8-group, butterfly gives full sum in every lane, fuses to v_add_f32_dpp.
// Clamp = v_med3_f32.

static constexpr float LR_ = 0.01f;

template <int CTRL>
__device__ __forceinline__ float dppx(float x) {
    return __int_as_float(
        __builtin_amdgcn_mov_dpp(__float_as_int(x), CTRL, 0xF, 0xF, true));
}
__device__ __forceinline__ void pin(float& x) { asm volatile("" : "+v"(x)); }

__global__ __launch_bounds__(256, 2) void solve_k(
    const float* __restrict__ spec, const float* __restrict__ W1,
    const float* __restrict__ b1,   const float* __restrict__ W2,
    const float* __restrict__ b2,   const float* __restrict__ R,
    float* __restrict__ out, int batch)
{
    __shared__ float sQs[384];   // Qs[i][j] = sQs[i*6+j], i<64, j<6 (includes -LR)
    __shared__ float sSs[240];   // Ss[j][k] = sSs[j*40+k], j<6, k<40 (includes -LR)

    const int t = threadIdx.x;

    // ---- per-block setup: Qs = -LR * W2 R^T R6, Ss = -LR * R6^T R ----
    if (t < 64) {
        float M[8];
        #pragma unroll
        for (int p = 0; p < 8; ++p) {
            float acc = 0.f;
            for (int k = 0; k < 40; ++k) acc = fmaf(W2[t*40+k], R[p*40+k], acc);
            M[p] = acc;
        }
        #pragma unroll
        for (int j = 0; j < 6; ++j) {
            float acc = 0.f;
            #pragma unroll
            for (int p = 0; p < 8; ++p) acc = fmaf(M[p], R[p*40+j], acc);
            sQs[t*6+j] = -LR_ * acc;
        }
    } else {
        for (int idx = t - 64; idx < 240; idx += 192) {
            int j = idx / 40, k = idx % 40;
            float acc = 0.f;
            #pragma unroll
            for (int p = 0; p < 8; ++p) acc = fmaf(R[p*40+j], R[p*40+k], acc);
            sSs[idx] = -LR_ * acc;
        }
    }
    __syncthreads();

    // ---- per-thread constants ----
    const int tid = blockIdx.x * 256 + t;
    const int s   = tid >> 3;    // sample
    const int sub = tid & 7;     // eighth of hidden dim
    const int ib  = sub * 8;
    const bool live = (s < batch);
    const int sl = live ? s : 0;

    float w1r[6][8], b1r[8], qsr[8][6];
    #pragma unroll
    for (int j = 0; j < 6; ++j)
        #pragma unroll
        for (int i = 0; i < 8; ++i)
            w1r[j][i] = W1[j*64 + ib + i];          // W1 is (6,64) row-major
    #pragma unroll
    for (int i = 0; i < 8; ++i) b1r[i] = b1[ib + i];
    #pragma unroll
    for (int i = 0; i < 8; ++i)
        #pragma unroll
        for (int j = 0; j < 6; ++j)
            qsr[i][j] = sQs[(ib + i)*6 + j];

    // es[j] = sum_k Ss[j][k] * (b2[k] - spec[k]);  esd = es/8 (fold into tree)
    float esd[6];
    #pragma unroll
    for (int j = 0; j < 6; ++j) esd[j] = 0.f;
    const float* sp = spec + sl * 40;
    for (int k = 0; k < 40; ++k) {
        float v = b2[k] - sp[k];
        #pragma unroll
        for (int j = 0; j < 6; ++j) esd[j] = fmaf(v, sSs[j*40+k], esd[j]);
    }
    #pragma unroll
    for (int j = 0; j < 6; ++j) esd[j] *= 0.125f;

    // ---- pin all loop-invariant values in VGPRs (defeat remat heuristic) ----
    #pragma unroll
    for (int j = 0; j < 6; ++j)
        #pragma unroll
        for (int i = 0; i < 8; ++i) pin(w1r[j][i]);
    #pragma unroll
    for (int i = 0; i < 8; ++i) pin(b1r[i]);
    #pragma unroll
    for (int i = 0; i < 8; ++i)
        #pragma unroll
        for (int j = 0; j < 6; ++j) pin(qsr[i][j]);
    #pragma unroll
    for (int j = 0; j < 6; ++j) pin(esd[j]);

    float u[6];
    #pragma unroll
    for (int j = 0; j < 6; ++j) u[j] = 0.5f;

    const float K = 2.8853900817779268f;  // 2*log2(e): exp2(K*t) = e^(2t)

    for (int step = 0; step < 200; ++step) {
        float h[8];
        #pragma unroll
        for (int i = 0; i < 8; ++i) {
            float tt = b1r[i];
            #pragma unroll
            for (int j = 0; j < 6; ++j) tt = fmaf(u[j], w1r[j][i], tt);
            float E = __builtin_amdgcn_exp2f(tt * K);                       // e^(2t)
            h[i] = fmaf(-2.0f, __builtin_amdgcn_rcpf(E + 1.0f), 1.0f);     // tanh(t)
        }
        // per-lane partial: g = (u + es)/8 + sum_i h[i] * Qs[i][:]
        float g[6];
        #pragma unroll
        for (int j = 0; j < 6; ++j) g[j] = fmaf(u[j], 0.125f, esd[j]);
        #pragma unroll
        for (int i = 0; i < 8; ++i)
            #pragma unroll
            for (int j = 0; j < 6; ++j)
                g[j] = fmaf(h[i], qsr[i][j], g[j]);
        // allreduce over the 8 lanes of this sample: xor1, xor2, xor7 (DPP only)
        #pragma unroll
        for (int j = 0; j < 6; ++j) {
            g[j] += dppx<0xB1>(g[j]);   // quad_perm [1,0,3,2]  (xor 1)
            g[j] += dppx<0x4E>(g[j]);   // quad_perm [2,3,0,1]  (xor 2)
            g[j] += dppx<0x141>(g[j]);  // row_half_mirror      (xor 7)
            u[j] = __builtin_amdgcn_fmed3f(g[j], 0.f, 1.f);
        }
    }

    if (live && sub == 0) {
        float* o = out + s * 6;
        #pragma unroll
        for (int j = 0; j < 6; ++j) o[j] = u[j];
    }
}

extern "C" void kernel_launch(void* const* d_in, const int* in_sizes, int n_in,
                              void* d_out, int out_size, void* d_ws, size_t ws_size,
                              hipStream_t stream)
{
    const float* spec = (const float*)d_in[0];  // (B,40)
    const float* W1   = (const float*)d_in[1];  // (6,64)
    const float* b1   = (const float*)d_in[2];  // (64,)
    const float* W2   = (const float*)d_in[3];  // (64,40)
    const float* b2   = (const float*)d_in[4];  // (40,)
    const float* R    = (const float*)d_in[5];  // (8,40)
    int batch = in_sizes[0] / 40;

    int threads = batch * 8;
    int blocks  = (threads + 255) / 256;
    hipLaunchKernelGGL(solve_k, dim3(blocks), dim3(256), 0, stream,
                       spec, W1, b1, W2, b2, R, (float*)d_out, batch);
}

// Round 4
// 151.988 us; speedup vs baseline: 1.2738x; 1.2738x over previous
//
#include <hip/hip_runtime.h>

// BackwardRPM: 16384 independent solves, 200 steps of
//   u <- clip(u - LR * (R^T (R (tanh(u W1 + b1) W2 + b2 - spec)))[:6])
// Algebra: Qs = -LR * W2 R^T R[:, :6] (64x6), Ss = -LR * R[:, :6]^T R (6x40),
//   es = Ss (b2 - spec) per sample. Step: t = u W1 + b1; h = tanh(t);
//   u = clip(u + h Qs + es).
// Further folds (R4): tanh(t) = 1 - 2*rcp(e^{2t}+1); pre-scale W1,b1 by
//   K=2*log2(e) so e^{2t} = exp2(uW1K + b1K); h = 1-2r =>
//   h Qs = sum_i Qs[i,:] + r_i * (-2 Qs[i,:]) -- fold sum_i Qs into the
//   per-thread constant, pre-scale Qs by -2. Loop per hidden unit: 6 FMA,
//   1 exp2, 1 add, 1 rcp. All FMAs packed fp32 (v_pk_fma_f32).
//
// R2/R3 lesson: allocator targeted 8 waves/SIMD (VGPR=64) and spilled the
// ~130 resident constants. amdgpu_waves_per_eu(2,2) pins the occupancy
// target to 2 waves/EU (= this grid: 2048 waves / 1024 SIMDs) -> 256 VGPRs.

static constexpr float LR_ = 0.01f;

typedef float v2f __attribute__((ext_vector_type(2)));

template <int CTRL>
__device__ __forceinline__ float dppx(float x) {
    return __int_as_float(
        __builtin_amdgcn_mov_dpp(__float_as_int(x), CTRL, 0xF, 0xF, true));
}
__device__ __forceinline__ void pin2(v2f& x) { asm volatile("" : "+v"(x)); }

__global__ __launch_bounds__(256)
__attribute__((amdgpu_waves_per_eu(2, 2)))
void solve_k(
    const float* __restrict__ spec, const float* __restrict__ W1,
    const float* __restrict__ b1,   const float* __restrict__ W2,
    const float* __restrict__ b2,   const float* __restrict__ R,
    float* __restrict__ out, int batch)
{
    __shared__ float sQs[64 * 7];  // Qs[i][j] = sQs[i*7+j] (stride 7: no 4-way bank conflict)
    __shared__ float sSs[240];     // Ss[j][k] = sSs[j*40+k] (includes -LR)

    const int t = threadIdx.x;

    // ---- per-block setup: Qs = -LR * W2 R^T R6, Ss = -LR * R6^T R ----
    if (t < 64) {
        float M[8];
        #pragma unroll
        for (int p = 0; p < 8; ++p) {
            float acc = 0.f;
            for (int k = 0; k < 40; ++k) acc = fmaf(W2[t*40+k], R[p*40+k], acc);
            M[p] = acc;
        }
        #pragma unroll
        for (int j = 0; j < 6; ++j) {
            float acc = 0.f;
            #pragma unroll
            for (int p = 0; p < 8; ++p) acc = fmaf(M[p], R[p*40+j], acc);
            sQs[t*7+j] = -LR_ * acc;
        }
    } else {
        for (int idx = t - 64; idx < 240; idx += 192) {
            int j = idx / 40, k = idx % 40;
            float acc = 0.f;
            #pragma unroll
            for (int p = 0; p < 8; ++p) acc = fmaf(R[p*40+j], R[p*40+k], acc);
            sSs[idx] = -LR_ * acc;
        }
    }
    __syncthreads();

    // ---- per-thread constants ----
    const int tid = blockIdx.x * 256 + t;
    const int s   = tid >> 3;    // sample
    const int sub = tid & 7;     // eighth of hidden dim
    const int ib  = sub * 8;
    const bool live = (s < batch);
    const int sl = live ? s : 0;

    const float K = 2.8853900817779268f;  // 2*log2(e)

    // W1 (6,64) row-major, pre-scaled by K, packed over hidden pairs.
    v2f w1kp[6][4], b1kp[4];
    #pragma unroll
    for (int j = 0; j < 6; ++j)
        #pragma unroll
        for (int ip = 0; ip < 4; ++ip) {
            w1kp[j][ip].x = K * W1[j*64 + ib + 2*ip];
            w1kp[j][ip].y = K * W1[j*64 + ib + 2*ip + 1];
        }
    #pragma unroll
    for (int ip = 0; ip < 4; ++ip) {
        b1kp[ip].x = K * b1[ib + 2*ip];
        b1kp[ip].y = K * b1[ib + 2*ip + 1];
    }

    // qs2p[i][m] = -2 * Qs[ib+i][2m..2m+1];  qc[j] = sum_i Qs[ib+i][j]
    v2f qs2p[8][3];
    float qc[6];
    #pragma unroll
    for (int j = 0; j < 6; ++j) qc[j] = 0.f;
    #pragma unroll
    for (int i = 0; i < 8; ++i)
        #pragma unroll
        for (int m = 0; m < 3; ++m) {
            float a = sQs[(ib + i)*7 + 2*m];
            float b = sQs[(ib + i)*7 + 2*m + 1];
            qs2p[i][m].x = -2.f * a;
            qs2p[i][m].y = -2.f * b;
            qc[2*m]   += a;
            qc[2*m+1] += b;
        }

    // es[j] = sum_k Ss[j][k]*(b2[k]-spec[k]);  c2[m] = es/8 + qc (packed)
    float es[6];
    #pragma unroll
    for (int j = 0; j < 6; ++j) es[j] = 0.f;
    const float* sp = spec + sl * 40;
    for (int k = 0; k < 40; ++k) {
        float v = b2[k] - sp[k];
        #pragma unroll
        for (int j = 0; j < 6; ++j) es[j] = fmaf(v, sSs[j*40+k], es[j]);
    }
    v2f c2[3];
    #pragma unroll
    for (int m = 0; m < 3; ++m) {
        c2[m].x = es[2*m]   * 0.125f + qc[2*m];
        c2[m].y = es[2*m+1] * 0.125f + qc[2*m+1];
    }

    // pin loop-invariants (belt+suspenders vs remat; budget is 256 VGPRs now)
    #pragma unroll
    for (int j = 0; j < 6; ++j)
        #pragma unroll
        for (int ip = 0; ip < 4; ++ip) pin2(w1kp[j][ip]);
    #pragma unroll
    for (int ip = 0; ip < 4; ++ip) pin2(b1kp[ip]);
    #pragma unroll
    for (int i = 0; i < 8; ++i)
        #pragma unroll
        for (int m = 0; m < 3; ++m) pin2(qs2p[i][m]);
    #pragma unroll
    for (int m = 0; m < 3; ++m) pin2(c2[m]);

    float u[6];
    #pragma unroll
    for (int j = 0; j < 6; ++j) u[j] = 0.5f;

    for (int step = 0; step < 200; ++step) {
        // r_i = rcp(exp2(uW1K + b1K) + 1)   (tanh = 1 - 2r, folded into consts)
        float r[8];
        #pragma unroll
        for (int ip = 0; ip < 4; ++ip) {
            v2f tt = b1kp[ip];
            #pragma unroll
            for (int j = 0; j < 6; ++j) {
                v2f ub = {u[j], u[j]};
                tt = __builtin_elementwise_fma(ub, w1kp[j][ip], tt);
            }
            v2f e1;
            e1.x = __builtin_amdgcn_exp2f(tt.x);
            e1.y = __builtin_amdgcn_exp2f(tt.y);
            e1 += (v2f){1.f, 1.f};
            r[2*ip]   = __builtin_amdgcn_rcpf(e1.x);
            r[2*ip+1] = __builtin_amdgcn_rcpf(e1.y);
        }
        // per-lane partial: g = u/8 + c + sum_i r_i * (-2 Qs[i,:])
        v2f g2[3];
        #pragma unroll
        for (int m = 0; m < 3; ++m) {
            v2f up = {u[2*m], u[2*m+1]};
            g2[m] = __builtin_elementwise_fma(up, (v2f){0.125f, 0.125f}, c2[m]);
        }
        #pragma unroll
        for (int i = 0; i < 8; ++i) {
            v2f hb = {r[i], r[i]};
            #pragma unroll
            for (int m = 0; m < 3; ++m)
                g2[m] = __builtin_elementwise_fma(hb, qs2p[i][m], g2[m]);
        }
        // allreduce over 8 lanes: xor1, xor2, xor7 (all DPP, VALU pipe)
        #pragma unroll
        for (int m = 0; m < 3; ++m) {
            float ga = g2[m].x, gb = g2[m].y;
            ga += dppx<0xB1>(ga);   gb += dppx<0xB1>(gb);    // quad_perm [1,0,3,2]
            ga += dppx<0x4E>(ga);   gb += dppx<0x4E>(gb);    // quad_perm [2,3,0,1]
            ga += dppx<0x141>(ga);  gb += dppx<0x141>(gb);   // row_half_mirror (xor 7)
            u[2*m]   = __builtin_amdgcn_fmed3f(ga, 0.f, 1.f);
            u[2*m+1] = __builtin_amdgcn_fmed3f(gb, 0.f, 1.f);
        }
    }

    if (live && sub == 0) {
        float* o = out + s * 6;
        #pragma unroll
        for (int j = 0; j < 6; ++j) o[j] = u[j];
    }
}

extern "C" void kernel_launch(void* const* d_in, const int* in_sizes, int n_in,
                              void* d_out, int out_size, void* d_ws, size_t ws_size,
                              hipStream_t stream)
{
    const float* spec = (const float*)d_in[0];  // (B,40)
    const float* W1   = (const float*)d_in[1];  // (6,64)
    const float* b1   = (const float*)d_in[2];  // (64,)
    const float* W2   = (const float*)d_in[3];  // (64,40)
    const float* b2   = (const float*)d_in[4];  // (40,)
    const float* R    = (const float*)d_in[5];  // (8,40)
    int batch = in_sizes[0] / 40;

    int threads = batch * 8;
    int blocks  = (threads + 255) / 256;
    hipLaunchKernelGGL(solve_k, dim3(blocks), dim3(256), 0, stream,
                       spec, W1, b1, W2, b2, R, (float*)d_out, batch);
}